// Round 14
// baseline (92.007 us; speedup 1.0000x reference)
//
#include <hip/hip_runtime.h>
#include <hip/hip_bf16.h>
#include <math.h>

#define B_  8
#define N_  16
#define L_  64
#define A_  16
#define DE  256
#define DH  64
#define H_  4
#define NL  1024
#define SCL (1.0f/128.0f)

__device__ __forceinline__ float dot4(float4 a, float4 b) {
    return a.x * b.x + a.y * b.y + a.z * b.z + a.w * b.w;
}

__device__ __align__(16) float g_q[B_ * A_ * DE];
__device__ __align__(16) float g_Pg[B_ * H_ * A_ * DE];
__device__ __align__(16) float2 g_SgCb[B_ * H_ * A_];
__device__ __align__(16) float g_scores[B_ * H_ * NL];
__device__ __align__(16) float g_coef[B_ * NL];
__device__ __align__(16) float g_mh[B_ * H_ * DH];

// ---------------------------------------------------------------------------
// Kernel 1: per (b,a): LN(curr) -> q -> P -> Pg/Sg/Cb;  + logmap0 coefs.
// ---------------------------------------------------------------------------
__global__ __launch_bounds__(256) void kPrep(
    const float* __restrict__ curr, const float* __restrict__ Wq,
    const float* __restrict__ Wk,
    const float* __restrict__ gq, const float* __restrict__ bq,
    const float* __restrict__ gk, const float* __restrict__ bk,
    const float* __restrict__ hyp)
{
    const int t = threadIdx.x;
    const int w = t >> 6, lane = t & 63;

    if (blockIdx.x >= 128) {
        const int row = (blockIdx.x - 128) * 4 + w;   // [0, 8192)
        float y = hyp[(size_t)row * DH + lane];
        float ss = y * y;
        #pragma unroll
        for (int m = 1; m < 64; m <<= 1) ss += __shfl_xor(ss, m);
        if (lane == 0) {
            float n = fmaxf(sqrtf(ss), 1e-6f);
            g_coef[row] = atanhf(fminf(n, 1.0f - 1e-5f)) / n;
        }
        return;
    }

    const int ba = blockIdx.x;
    const int b = ba >> 4, a = ba & 15;

    __shared__ float lnb[DE];
    __shared__ float qsb[DE];
    __shared__ float rA[4], rB[4];
    __shared__ float r2[4][8];

    const float xv = curr[(size_t)ba * DE + t];
    float s1 = xv, s2 = xv * xv;
    #pragma unroll
    for (int m = 1; m < 64; m <<= 1) { s1 += __shfl_xor(s1, m); s2 += __shfl_xor(s2, m); }
    if (lane == 0) { rA[w] = s1; rB[w] = s2; }
    __syncthreads();
    s1 = rA[0] + rA[1] + rA[2] + rA[3];
    s2 = rB[0] + rB[1] + rB[2] + rB[3];
    const float mean = s1 * (1.0f / DE);
    const float var  = s2 * (1.0f / DE) - mean * mean;
    const float inv  = rsqrtf(var + 1e-5f);
    lnb[t] = (xv - mean) * inv * gq[t] + bq[t];
    __syncthreads();

    {
        const float4* wr = (const float4*)(Wq + (size_t)t * DE);
        const float4* lx = (const float4*)lnb;
        float qa = 0.0f;
        #pragma unroll 4
        for (int k = 0; k < DE / 4; k++) qa += dot4(lx[k], wr[k]);
        qsb[t] = qa;
    }
    __syncthreads();

    float pv[H_];
    #pragma unroll
    for (int h = 0; h < H_; h++) {
        float acc = 0.0f;
        #pragma unroll 4
        for (int d = 0; d < 64; d++)
            acc = fmaf(qsb[h * 64 + d], Wk[(size_t)(h * 64 + d) * DE + t], acc);
        pv[h] = acc * SCL;
    }

    const float gv = gk[t], bv = bk[t];
    float v8[8];
    #pragma unroll
    for (int h = 0; h < H_; h++) {
        float pgv = pv[h] * gv;
        g_Pg[(((size_t)b * H_ + h) * A_ + a) * DE + t] = pgv;
        v8[2*h]   = pgv;
        v8[2*h+1] = pv[h] * bv;
    }
    #pragma unroll
    for (int m = 1; m < 64; m <<= 1) {
        #pragma unroll
        for (int i = 0; i < 8; i++) v8[i] += __shfl_xor(v8[i], m);
    }
    if (lane == 0) {
        #pragma unroll
        for (int i = 0; i < 8; i++) r2[w][i] = v8[i];
    }
    __syncthreads();
    if (t < 4) {
        float sg = r2[0][2*t]   + r2[1][2*t]   + r2[2][2*t]   + r2[3][2*t];
        float cb = r2[0][2*t+1] + r2[1][2*t+1] + r2[2][2*t+1] + r2[3][2*t+1];
        g_SgCb[(b * H_ + t) * A_ + a] = make_float2(sg, cb);
    }
}

// ---------------------------------------------------------------------------
// Kernel 2: scores — one wave per nl row; Pg[b] staged in LDS.
// Active support: mask == 1 (faithful reference reading).
// ---------------------------------------------------------------------------
__global__ __launch_bounds__(512) void kScores(
    const float* __restrict__ demo, const int* __restrict__ mask)
{
    __shared__ float pgs[H_ * A_ * DE];   // 64 KB
    __shared__ float2 sgcb[H_ * A_];
    const int b = blockIdx.y;
    const int t = threadIdx.x;

    {
        const float4* src = (const float4*)(g_Pg + (size_t)b * H_ * A_ * DE);
        float4* dst = (float4*)pgs;
        #pragma unroll
        for (int i = 0; i < 8; i++) dst[t + i * 512] = src[t + i * 512];
        if (t < H_ * A_) sgcb[t] = g_SgCb[b * H_ * A_ + t];
    }
    __syncthreads();

    const int wid = t >> 6, lane = t & 63;
    const int nl = blockIdx.x * 8 + wid;
    const float4* pgs4 = (const float4*)pgs;

    float sc0, sc1, sc2, sc3;
    if (mask[b * NL + nl] == 1) {
        sc0 = sc1 = sc2 = sc3 = 0.0f;
        #pragma unroll 1
        for (int a = 0; a < A_; a++) {
            const float4* xr = (const float4*)(demo + (((size_t)(b * NL + nl)) * A_ + a) * DE);
            const float4 x = xr[lane];
            float s1 = x.x + x.y + x.z + x.w;
            float s2 = dot4(x, x);
            float d0 = dot4(pgs4[(0 * A_ + a) * (DE / 4) + lane], x);
            float d1 = dot4(pgs4[(1 * A_ + a) * (DE / 4) + lane], x);
            float d2 = dot4(pgs4[(2 * A_ + a) * (DE / 4) + lane], x);
            float d3 = dot4(pgs4[(3 * A_ + a) * (DE / 4) + lane], x);
            #pragma unroll
            for (int m = 1; m < 64; m <<= 1) {
                s1 += __shfl_xor(s1, m); s2 += __shfl_xor(s2, m);
                d0 += __shfl_xor(d0, m); d1 += __shfl_xor(d1, m);
                d2 += __shfl_xor(d2, m); d3 += __shfl_xor(d3, m);
            }
            const float mean = s1 * (1.0f / 256.0f);
            const float var  = fmaf(-mean, mean, s2 * (1.0f / 256.0f));
            const float invs = rsqrtf(var + 1e-5f);
            const float2 c0 = sgcb[0 * A_ + a];
            const float2 c1 = sgcb[1 * A_ + a];
            const float2 c2 = sgcb[2 * A_ + a];
            const float2 c3 = sgcb[3 * A_ + a];
            sc0 += (d0 - mean * c0.x) * invs + c0.y;
            sc1 += (d1 - mean * c1.x) * invs + c1.y;
            sc2 += (d2 - mean * c2.x) * invs + c2.y;
            sc3 += (d3 - mean * c3.x) * invs + c3.y;
        }
    } else {
        sc0 = sc1 = sc2 = sc3 = -INFINITY;
    }
    if (lane == 0) {
        g_scores[((size_t)b * H_ + 0) * NL + nl] = sc0;
        g_scores[((size_t)b * H_ + 1) * NL + nl] = sc1;
        g_scores[((size_t)b * H_ + 2) * NL + nl] = sc2;
        g_scores[((size_t)b * H_ + 3) * NL + nl] = sc3;
    }
}

// ---------------------------------------------------------------------------
// Kernel 3: softmax per (b,h); attn (FLOAT32 out); m_h (per-b v rows).
// ---------------------------------------------------------------------------
__global__ __launch_bounds__(256) void kSoftmax(
    const float* __restrict__ hyp, float* __restrict__ attn)
{
    const int bh = blockIdx.x, b = bh >> 2, t = threadIdx.x;
    const int w = t >> 6, lane = t & 63;
    __shared__ float pl[NL];
    __shared__ float rmax[4], rsum[4];
    __shared__ float4 red4[16][16];

    const float s0 = g_scores[(size_t)bh * NL + t];
    const float s1 = g_scores[(size_t)bh * NL + t + 256];
    const float s2 = g_scores[(size_t)bh * NL + t + 512];
    const float s3 = g_scores[(size_t)bh * NL + t + 768];

    float mx = fmaxf(fmaxf(s0, s1), fmaxf(s2, s3));
    #pragma unroll
    for (int m = 1; m < 64; m <<= 1) mx = fmaxf(mx, __shfl_xor(mx, m));
    if (lane == 0) rmax[w] = mx;
    __syncthreads();
    mx = fmaxf(fmaxf(rmax[0], rmax[1]), fmaxf(rmax[2], rmax[3]));

    const float p0 = expf(s0 - mx), p1 = expf(s1 - mx);
    const float p2 = expf(s2 - mx), p3 = expf(s3 - mx);
    float ps = (p0 + p1) + (p2 + p3);
    #pragma unroll
    for (int m = 1; m < 64; m <<= 1) ps += __shfl_xor(ps, m);
    if (lane == 0) rsum[w] = ps;
    __syncthreads();
    ps = rsum[0] + rsum[1] + rsum[2] + rsum[3];
    const float inv = 1.0f / ps;

    {
        float a0 = p0 * inv, a1 = p1 * inv, a2 = p2 * inv, a3 = p3 * inv;
        attn[(size_t)bh * NL + t      ] = a0;
        attn[(size_t)bh * NL + t + 256] = a1;
        attn[(size_t)bh * NL + t + 512] = a2;
        attn[(size_t)bh * NL + t + 768] = a3;
        pl[t      ] = a0 * g_coef[b * NL + t      ];
        pl[t + 256] = a1 * g_coef[b * NL + t + 256];
        pl[t + 512] = a2 * g_coef[b * NL + t + 512];
        pl[t + 768] = a3 * g_coef[b * NL + t + 768];
    }
    __syncthreads();

    const int gg = t >> 4, dq = t & 15;
    float4 acc = make_float4(0.f, 0.f, 0.f, 0.f);
    const float4* vb = ((const float4*)hyp) + ((size_t)b * NL + gg * 64) * (DH / 4) + dq;
    #pragma unroll 8
    for (int i = 0; i < 64; i++) {
        const float wv = pl[gg * 64 + i];
        const float4 v = vb[(size_t)i * (DH / 4)];
        acc.x = fmaf(wv, v.x, acc.x);
        acc.y = fmaf(wv, v.y, acc.y);
        acc.z = fmaf(wv, v.z, acc.z);
        acc.w = fmaf(wv, v.w, acc.w);
    }
    red4[gg][dq] = acc;
    __syncthreads();
    if (t < 16) {
        float4 s = red4[0][t];
        #pragma unroll
        for (int g2 = 1; g2 < 16; g2++) {
            s.x += red4[g2][t].x; s.y += red4[g2][t].y;
            s.z += red4[g2][t].z; s.w += red4[g2][t].w;
        }
        ((float4*)(g_mh + (size_t)bh * DH))[t] = s;
    }
}

// ---------------------------------------------------------------------------
// Kernel 4: exp/log map chain + radius clamp -> curr_hyp (FLOAT32 out).
// ---------------------------------------------------------------------------
__global__ __launch_bounds__(64) void kFinal(float* __restrict__ out)
{
    const int b = blockIdx.x, d = threadIdx.x;
    float macc = 0.0f;
    #pragma unroll
    for (int h = 0; h < H_; h++) {
        const float m = g_mh[((size_t)b * H_ + h) * DH + d];
        float ss = m * m;
        #pragma unroll
        for (int k = 1; k < 64; k <<= 1) ss += __shfl_xor(ss, k);
        const float n1 = fmaxf(sqrtf(ss), 1e-6f);
        const float y  = tanhf(n1) * (m / n1);
        float s2 = y * y;
        #pragma unroll
        for (int k = 1; k < 64; k <<= 1) s2 += __shfl_xor(s2, k);
        const float n2 = fmaxf(sqrtf(s2), 1e-6f);
        macc += atanhf(fminf(n2, 1.0f - 1e-5f)) * (y / n2);
    }
    const float mm = macc * 0.25f;
    float s3 = mm * mm;
    #pragma unroll
    for (int k = 1; k < 64; k <<= 1) s3 += __shfl_xor(s3, k);
    const float n3 = fmaxf(sqrtf(s3), 1e-6f);
    float ch = tanhf(n3) * (mm / n3);
    float s4 = ch * ch;
    #pragma unroll
    for (int k = 1; k < 64; k <<= 1) s4 += __shfl_xor(s4, k);
    const float n4 = fmaxf(sqrtf(s4), 1e-6f);
    ch *= fminf((1.0f - 1e-5f) / n4, 1.0f);
    out[(size_t)b * DH + d] = ch;
}

// ---------------------------------------------------------------------------
extern "C" void kernel_launch(void* const* d_in, const int* in_sizes, int n_in,
                              void* d_out, int out_size, void* d_ws, size_t ws_size,
                              hipStream_t stream)
{
    const float* curr = (const float*)d_in[0];
    const float* demo = (const float*)d_in[1];
    const float* hyp  = (const float*)d_in[2];
    const int*   mask = (const int*)d_in[3];
    const float* Wq   = (const float*)d_in[4];
    const float* Wk   = (const float*)d_in[5];
    const float* gq   = (const float*)d_in[6];
    const float* bq   = (const float*)d_in[7];
    const float* gk   = (const float*)d_in[8];
    const float* bk   = (const float*)d_in[9];

    float* out = (float*)d_out;    // reference outputs are FLOAT32

    kPrep<<<dim3(128 + 2048), 256, 0, stream>>>(curr, Wq, Wk, gq, bq, gk, bk, hyp);
    kScores<<<dim3(128, 8), 512, 0, stream>>>(demo, mask);
    kSoftmax<<<32, 256, 0, stream>>>(hyp, out + B_ * DH);
    kFinal<<<8, 64, 0, stream>>>(out);
}

// Round 15
// 61.145 us; speedup vs baseline: 1.5047x; 1.5047x over previous
//
#include <hip/hip_runtime.h>
#include <hip/hip_bf16.h>
#include <math.h>

#define B_  8
#define N_  16
#define L_  64
#define A_  16
#define DE  256
#define DH  64
#define H_  4
#define NL  1024
#define SCL (1.0f/128.0f)

__device__ __forceinline__ float dot4(float4 a, float4 b) {
    return a.x * b.x + a.y * b.y + a.z * b.z + a.w * b.w;
}

__device__ __align__(16) float g_Pg[B_ * H_ * A_ * DE];
__device__ __align__(16) float2 g_SgCb[B_ * H_ * A_];
__device__ __align__(16) float g_scores[B_ * H_ * NL];
__device__ __align__(16) float g_coef[B_ * NL];
__device__ __align__(16) float g_mh[B_ * H_ * DH];

// ---------------------------------------------------------------------------
// Kernel 1: per (b,a): LN(curr) -> q -> P -> Pg/Sg/Cb;  + logmap0 coefs.
// ---------------------------------------------------------------------------
__global__ __launch_bounds__(256) void kPrep(
    const float* __restrict__ curr, const float* __restrict__ Wq,
    const float* __restrict__ Wk,
    const float* __restrict__ gq, const float* __restrict__ bq,
    const float* __restrict__ gk, const float* __restrict__ bk,
    const float* __restrict__ hyp)
{
    const int t = threadIdx.x;
    const int w = t >> 6, lane = t & 63;

    if (blockIdx.x >= 128) {
        const int row = (blockIdx.x - 128) * 4 + w;   // [0, 8192)
        float y = hyp[(size_t)row * DH + lane];
        float ss = y * y;
        #pragma unroll
        for (int m = 1; m < 64; m <<= 1) ss += __shfl_xor(ss, m);
        if (lane == 0) {
            float n = fmaxf(sqrtf(ss), 1e-6f);
            g_coef[row] = atanhf(fminf(n, 1.0f - 1e-5f)) / n;
        }
        return;
    }

    const int ba = blockIdx.x;
    const int b = ba >> 4, a = ba & 15;

    __shared__ float lnb[DE];
    __shared__ float qsb[DE];
    __shared__ float rA[4], rB[4];
    __shared__ float r2[4][8];

    const float xv = curr[(size_t)ba * DE + t];
    float s1 = xv, s2 = xv * xv;
    #pragma unroll
    for (int m = 1; m < 64; m <<= 1) { s1 += __shfl_xor(s1, m); s2 += __shfl_xor(s2, m); }
    if (lane == 0) { rA[w] = s1; rB[w] = s2; }
    __syncthreads();
    s1 = rA[0] + rA[1] + rA[2] + rA[3];
    s2 = rB[0] + rB[1] + rB[2] + rB[3];
    const float mean = s1 * (1.0f / DE);
    const float var  = s2 * (1.0f / DE) - mean * mean;
    const float inv  = rsqrtf(var + 1e-5f);
    lnb[t] = (xv - mean) * inv * gq[t] + bq[t];
    __syncthreads();

    {
        const float4* wr = (const float4*)(Wq + (size_t)t * DE);
        const float4* lx = (const float4*)lnb;
        float qa = 0.0f;
        #pragma unroll 4
        for (int k = 0; k < DE / 4; k++) qa += dot4(lx[k], wr[k]);
        qsb[t] = qa;
    }
    __syncthreads();

    float pv[H_];
    #pragma unroll
    for (int h = 0; h < H_; h++) {
        float acc = 0.0f;
        #pragma unroll 4
        for (int d = 0; d < 64; d++)
            acc = fmaf(qsb[h * 64 + d], Wk[(size_t)(h * 64 + d) * DE + t], acc);
        pv[h] = acc * SCL;
    }

    const float gv = gk[t], bv = bk[t];
    float v8[8];
    #pragma unroll
    for (int h = 0; h < H_; h++) {
        float pgv = pv[h] * gv;
        g_Pg[(((size_t)b * H_ + h) * A_ + a) * DE + t] = pgv;
        v8[2*h]   = pgv;
        v8[2*h+1] = pv[h] * bv;
    }
    #pragma unroll
    for (int m = 1; m < 64; m <<= 1) {
        #pragma unroll
        for (int i = 0; i < 8; i++) v8[i] += __shfl_xor(v8[i], m);
    }
    if (lane == 0) {
        #pragma unroll
        for (int i = 0; i < 8; i++) r2[w][i] = v8[i];
    }
    __syncthreads();
    if (t < 4) {
        float sg = r2[0][2*t]   + r2[1][2*t]   + r2[2][2*t]   + r2[3][2*t];
        float cb = r2[0][2*t+1] + r2[1][2*t+1] + r2[2][2*t+1] + r2[3][2*t+1];
        g_SgCb[(b * H_ + t) * A_ + a] = make_float2(sg, cb);
    }
}

// ---------------------------------------------------------------------------
// Kernel 2: scores — 16-lane-group design. grid (64,8), 512 thr.
// Each wave: 2 rows; per row, group g handles a = p*4+g (p=0..3),
// 16-lane butterflies (masks 1,2,4,8), final cross-group (16,32).
// ---------------------------------------------------------------------------
__global__ __launch_bounds__(512) void kScores(
    const float* __restrict__ demo, const int* __restrict__ mask)
{
    __shared__ float pgs[H_ * A_ * DE];   // 64 KB
    __shared__ float2 sgcb[H_ * A_];
    const int b = blockIdx.y;
    const int t = threadIdx.x;

    {
        const float4* src = (const float4*)(g_Pg + (size_t)b * H_ * A_ * DE);
        float4* dst = (float4*)pgs;
        #pragma unroll
        for (int i = 0; i < 8; i++) dst[t + i * 512] = src[t + i * 512];
        if (t < H_ * A_) sgcb[t] = g_SgCb[b * H_ * A_ + t];
    }
    __syncthreads();

    const int wid = t >> 6, lane = t & 63;
    const int g = lane >> 4, li = lane & 15;
    const float4* pgs4 = (const float4*)pgs;

    #pragma unroll
    for (int r = 0; r < 2; r++) {
        const int nl = blockIdx.x * 16 + r * 8 + wid;
        float sc0, sc1, sc2, sc3;
        if (mask[b * NL + nl] == 1) {
            sc0 = sc1 = sc2 = sc3 = 0.0f;
            const float4* base4 = ((const float4*)demo) + ((size_t)(b * NL + nl) * A_) * (DE / 4);
            #pragma unroll
            for (int p = 0; p < 4; p++) {
                const int a = p * 4 + g;
                const float4* xr = base4 + a * (DE / 4);
                float4 x0 = xr[li], x1 = xr[16 + li], x2 = xr[32 + li], x3 = xr[48 + li];
                const float4* p0 = pgs4 + (0 * A_ + a) * (DE / 4);
                const float4* p1 = pgs4 + (1 * A_ + a) * (DE / 4);
                const float4* p2 = pgs4 + (2 * A_ + a) * (DE / 4);
                const float4* p3 = pgs4 + (3 * A_ + a) * (DE / 4);

                float s1 = (x0.x + x0.y + x0.z + x0.w) + (x1.x + x1.y + x1.z + x1.w)
                         + (x2.x + x2.y + x2.z + x2.w) + (x3.x + x3.y + x3.z + x3.w);
                float s2 = dot4(x0, x0) + dot4(x1, x1) + dot4(x2, x2) + dot4(x3, x3);
                float d0 = dot4(p0[li], x0) + dot4(p0[16+li], x1) + dot4(p0[32+li], x2) + dot4(p0[48+li], x3);
                float d1 = dot4(p1[li], x0) + dot4(p1[16+li], x1) + dot4(p1[32+li], x2) + dot4(p1[48+li], x3);
                float d2 = dot4(p2[li], x0) + dot4(p2[16+li], x1) + dot4(p2[32+li], x2) + dot4(p2[48+li], x3);
                float d3 = dot4(p3[li], x0) + dot4(p3[16+li], x1) + dot4(p3[32+li], x2) + dot4(p3[48+li], x3);

                #pragma unroll
                for (int m = 1; m < 16; m <<= 1) {
                    s1 += __shfl_xor(s1, m); s2 += __shfl_xor(s2, m);
                    d0 += __shfl_xor(d0, m); d1 += __shfl_xor(d1, m);
                    d2 += __shfl_xor(d2, m); d3 += __shfl_xor(d3, m);
                }
                const float mean = s1 * (1.0f / 256.0f);
                const float var  = fmaf(-mean, mean, s2 * (1.0f / 256.0f));
                const float invs = rsqrtf(var + 1e-5f);
                const float2 c0 = sgcb[0 * A_ + a];
                const float2 c1 = sgcb[1 * A_ + a];
                const float2 c2 = sgcb[2 * A_ + a];
                const float2 c3 = sgcb[3 * A_ + a];
                sc0 += (d0 - mean * c0.x) * invs + c0.y;
                sc1 += (d1 - mean * c1.x) * invs + c1.y;
                sc2 += (d2 - mean * c2.x) * invs + c2.y;
                sc3 += (d3 - mean * c3.x) * invs + c3.y;
            }
            #pragma unroll
            for (int m = 16; m < 64; m <<= 1) {
                sc0 += __shfl_xor(sc0, m); sc1 += __shfl_xor(sc1, m);
                sc2 += __shfl_xor(sc2, m); sc3 += __shfl_xor(sc3, m);
            }
        } else {
            sc0 = sc1 = sc2 = sc3 = -INFINITY;
        }
        if (lane == 0) {
            g_scores[((size_t)b * H_ + 0) * NL + nl] = sc0;
            g_scores[((size_t)b * H_ + 1) * NL + nl] = sc1;
            g_scores[((size_t)b * H_ + 2) * NL + nl] = sc2;
            g_scores[((size_t)b * H_ + 3) * NL + nl] = sc3;
        }
    }
}

// ---------------------------------------------------------------------------
// Kernel 3: softmax per (b,h), 1024 threads; attn f32; wave-parallel PV.
// ---------------------------------------------------------------------------
__global__ __launch_bounds__(1024) void kSoftmax(
    const float* __restrict__ hyp, float* __restrict__ attn)
{
    const int bh = blockIdx.x, b = bh >> 2, t = threadIdx.x;
    const int w = t >> 6, lane = t & 63;
    __shared__ float pl[NL];
    __shared__ float rmax[16], rsum[16];
    __shared__ float part[16][DH];

    const float s = g_scores[(size_t)bh * NL + t];
    float mx = s;
    #pragma unroll
    for (int m = 1; m < 64; m <<= 1) mx = fmaxf(mx, __shfl_xor(mx, m));
    if (lane == 0) rmax[w] = mx;
    __syncthreads();
    mx = rmax[0];
    #pragma unroll
    for (int i = 1; i < 16; i++) mx = fmaxf(mx, rmax[i]);

    const float p = expf(s - mx);
    float ps = p;
    #pragma unroll
    for (int m = 1; m < 64; m <<= 1) ps += __shfl_xor(ps, m);
    if (lane == 0) rsum[w] = ps;
    __syncthreads();
    ps = rsum[0];
    #pragma unroll
    for (int i = 1; i < 16; i++) ps += rsum[i];

    const float a0 = p / ps;
    attn[(size_t)bh * NL + t] = a0;
    pl[t] = a0 * g_coef[b * NL + t];
    __syncthreads();

    // PV: wave w owns rows [w*64, w*64+64), lane = d.
    float acc = 0.0f;
    const float* vb = hyp + ((size_t)b * NL + w * 64) * DH + lane;
    #pragma unroll 8
    for (int i = 0; i < 64; i++)
        acc = fmaf(pl[w * 64 + i], vb[(size_t)i * DH], acc);
    part[w][lane] = acc;
    __syncthreads();
    if (t < DH) {
        float sum = part[0][t];
        #pragma unroll
        for (int i = 1; i < 16; i++) sum += part[i][t];
        g_mh[(size_t)bh * DH + t] = sum;
    }
}

// ---------------------------------------------------------------------------
// Kernel 4: exp/log map chain + radius clamp -> curr_hyp (f32).
// ---------------------------------------------------------------------------
__global__ __launch_bounds__(64) void kFinal(float* __restrict__ out)
{
    const int b = blockIdx.x, d = threadIdx.x;
    float macc = 0.0f;
    #pragma unroll
    for (int h = 0; h < H_; h++) {
        const float m = g_mh[((size_t)b * H_ + h) * DH + d];
        float ss = m * m;
        #pragma unroll
        for (int k = 1; k < 64; k <<= 1) ss += __shfl_xor(ss, k);
        const float n1 = fmaxf(sqrtf(ss), 1e-6f);
        const float y  = tanhf(n1) * (m / n1);
        float s2 = y * y;
        #pragma unroll
        for (int k = 1; k < 64; k <<= 1) s2 += __shfl_xor(s2, k);
        const float n2 = fmaxf(sqrtf(s2), 1e-6f);
        macc += atanhf(fminf(n2, 1.0f - 1e-5f)) * (y / n2);
    }
    const float mm = macc * 0.25f;
    float s3 = mm * mm;
    #pragma unroll
    for (int k = 1; k < 64; k <<= 1) s3 += __shfl_xor(s3, k);
    const float n3 = fmaxf(sqrtf(s3), 1e-6f);
    float ch = tanhf(n3) * (mm / n3);
    float s4 = ch * ch;
    #pragma unroll
    for (int k = 1; k < 64; k <<= 1) s4 += __shfl_xor(s4, k);
    const float n4 = fmaxf(sqrtf(s4), 1e-6f);
    ch *= fminf((1.0f - 1e-5f) / n4, 1.0f);
    out[(size_t)b * DH + d] = ch;
}

// ---------------------------------------------------------------------------
extern "C" void kernel_launch(void* const* d_in, const int* in_sizes, int n_in,
                              void* d_out, int out_size, void* d_ws, size_t ws_size,
                              hipStream_t stream)
{
    const float* curr = (const float*)d_in[0];
    const float* demo = (const float*)d_in[1];
    const float* hyp  = (const float*)d_in[2];
    const int*   mask = (const int*)d_in[3];
    const float* Wq   = (const float*)d_in[4];
    const float* Wk   = (const float*)d_in[5];
    const float* gq   = (const float*)d_in[6];
    const float* bq   = (const float*)d_in[7];
    const float* gk   = (const float*)d_in[8];
    const float* bk   = (const float*)d_in[9];

    float* out = (float*)d_out;   // f32 outputs

    kPrep<<<dim3(128 + 2048), 256, 0, stream>>>(curr, Wq, Wk, gq, bq, gk, bk, hyp);
    kScores<<<dim3(64, 8), 512, 0, stream>>>(demo, mask);
    kSoftmax<<<32, 1024, 0, stream>>>(hyp, out + B_ * DH);
    kFinal<<<8, 64, 0, stream>>>(out);
}